// Round 3
// baseline (1327.254 us; speedup 1.0000x reference)
//
#include <hip/hip_runtime.h>
#include <math.h>

// GlobalSceneTokenizer fused pipeline with on-device dtype probe.
// pooled[b,c] = max_{i,k} LN2(gelu(LN1(gin@w1+b1))@w2+b2)[c]; final 2 MLPs on [4,256].
// All kernels branch on a runtime flag (f32 vs bf16 input buffers) written by k_probe.

#define LN_EPS 1e-5f

typedef __attribute__((ext_vector_type(8))) short bf16x8;
typedef __attribute__((ext_vector_type(4))) float f32x4;

__device__ __forceinline__ float bf2f(unsigned short u) {
    return __uint_as_float(((unsigned int)u) << 16);
}
__device__ __forceinline__ unsigned short f2bf(float f) {
    unsigned int x = __float_as_uint(f);
    return (unsigned short)((x + 0x7FFFu + ((x >> 16) & 1u)) >> 16);  // RNE
}
__device__ __forceinline__ unsigned int fenc(float f) {
    unsigned int u = __float_as_uint(f);
    return (u & 0x80000000u) ? ~u : (u | 0x80000000u);
}
__device__ __forceinline__ float fdec(unsigned int u) {
    return __uint_as_float((u & 0x80000000u) ? (u & 0x7FFFFFFFu) : ~u);
}
__device__ __forceinline__ float gelu_exact(float x) {
    return 0.5f * x * (1.0f + erff(x * 0.70710678118654752440f));
}
template<bool F32>
__device__ __forceinline__ float ldE(const void* p, size_t i) {
    return F32 ? ((const float*)p)[i] : bf2f(((const unsigned short*)p)[i]);
}

// ---------------- K_probe: detect f32 (flag=1) vs bf16 (flag=0) -----------
// bf16 xyz in [0,1): every halfword has sign=0 and value <= 0x3F80.
// f32 xyz: low-mantissa halfwords are ~uniform random -> many violations.
__global__ __launch_bounds__(64) void k_probe(
    const unsigned short* __restrict__ x, int* __restrict__ flag)
{
    int t = threadIdx.x;
    int viol = 0;
    #pragma unroll
    for (int q = 0; q < 4; ++q) {
        unsigned short h = x[t * 4 + q];
        viol += ((h & 0x8000u) != 0 || h > 0x3F80u) ? 1 : 0;
    }
    #pragma unroll
    for (int m = 1; m <= 32; m <<= 1) viol += __shfl_xor(viol, m);
    if (t == 0) *flag = (viol >= 4) ? 1 : 0;
}

// ---------------- K_prep: w2T, w1T (K-pad 192), pooled init ----------------
template<bool F32>
__device__ __forceinline__ void prep_body(
    const void* w1, const void* w2,
    unsigned short* w2T, unsigned short* w1T, unsigned int* pooled)
{
    int t = threadIdx.x;
    if (blockIdx.x == 16) {
        for (int k = 0; k < 192; ++k)
            w1T[t * 192 + k] = (k < 187) ? f2bf(ldE<F32>(w1, (size_t)k * 256 + t))
                                         : (unsigned short)0;
        unsigned int idv = fenc(-1e19f);
        for (int q = t; q < 1024; q += 256) pooled[q] = idv;
        return;
    }
    __shared__ unsigned short tile[64][65];
    int tr = blockIdx.x >> 2, tc = blockIdx.x & 3;
    #pragma unroll
    for (int rr = 0; rr < 16; ++rr) {
        int kl = rr * 4 + (t >> 6), nl = t & 63;
        tile[kl][nl] = f2bf(ldE<F32>(w2, (size_t)(tr * 64 + kl) * 256 + tc * 64 + nl));
    }
    __syncthreads();
    #pragma unroll
    for (int rr = 0; rr < 16; ++rr) {
        int nl = rr * 4 + (t >> 6), kl = t & 63;
        w2T[(tc * 64 + nl) * 256 + tr * 64 + kl] = tile[kl][nl];
    }
}
__global__ __launch_bounds__(256) void k_prep(
    const void* w1, const void* w2, unsigned short* w2T, unsigned short* w1T,
    unsigned int* pooled, const int* __restrict__ flag)
{
    if (*flag) prep_body<true>(w1, w2, w2T, w1T, pooled);
    else       prep_body<false>(w1, w2, w2T, w1T, pooled);
}

// ---------------- K_main ---------------------------------------------------
template<bool F32>
__device__ __forceinline__ void main_body(
    const void* xyz, const void* pf,
    const unsigned short* __restrict__ w1T, const unsigned short* __restrict__ w2T,
    const void* b1, const void* g1, const void* be1,
    const void* b2, const void* g2, const void* be2,
    unsigned int* __restrict__ pooled)
{
    __shared__ __align__(16) unsigned short a1s[64 * 200]; // A: 192 K + 8 pad
    __shared__ __align__(16) unsigned short h1s[64 * 264]; // 256 cols + 8 pad
    __shared__ float embs[2][96];
    __shared__ float reds[64][4][2];
    __shared__ float musig[64][2];
    __shared__ int   idxs[64];
    __shared__ float ctr[2][3];

    const int N = 4096;
    int tid = threadIdx.x, wv = tid >> 6, lane = tid & 63;
    int lo16 = lane & 15, quad = lane >> 4;
    int b = blockIdx.x & 3;
    int i0 = (blockIdx.x >> 2) * 2;
    size_t base = (size_t)b * N;
    size_t xbase = base * 3;

    // P0a: centers
    if (tid < 6) {
        int p = tid / 3, a = tid - 3 * p;
        ctr[p][a] = ldE<F32>(xyz, xbase + (size_t)(i0 + p) * 3 + a);
    }
    // P0b: abs sin-emb (dim 96) for both centers
    if (tid < 192) {
        int p = (tid >= 96) ? 1 : 0, cc = tid - 96 * p;
        int a = cc >> 5, wI = cc & 31;
        int jf = (wI < 16) ? wI : (wI - 16);
        float coord = ldE<F32>(xyz, xbase + (size_t)(i0 + p) * 3 + a);
        float fr = expf(-9.210340371976184f * (float)jf * (1.f / 15.f));
        float ang = coord * fr;
        embs[p][cc] = (wI < 16) ? sinf(ang) : cosf(ang);
    }
    // P0c: ball query (waves 0/1): first 32 in-ball by ascending index
    if (wv < 2) {
        int i = i0 + wv;
        float cx = ldE<F32>(xyz, xbase + (size_t)i * 3 + 0);
        float cy = ldE<F32>(xyz, xbase + (size_t)i * 3 + 1);
        float cz = ldE<F32>(xyz, xbase + (size_t)i * 3 + 2);
        int cnt = 0, firstj = -1;
        for (int c0 = 0; c0 < N && cnt < 32; c0 += 64) {
            int j = c0 + lane;
            float dx = __fsub_rn(ldE<F32>(xyz, xbase + (size_t)j * 3 + 0), cx);
            float dy = __fsub_rn(ldE<F32>(xyz, xbase + (size_t)j * 3 + 1), cy);
            float dz = __fsub_rn(ldE<F32>(xyz, xbase + (size_t)j * 3 + 2), cz);
            float sq = __fadd_rn(__fadd_rn(__fmul_rn(dx, dx), __fmul_rn(dy, dy)),
                                 __fmul_rn(dz, dz));
            bool inball = !((double)sq > (double)0.16 * 0.16);
            unsigned long long m = __ballot(inball);
            int rank = __popcll(m & ((1ull << lane) - 1ull));
            if (inball && (cnt + rank) < 32) idxs[wv * 32 + cnt + rank] = j;
            if (firstj < 0 && m != 0ull) firstj = c0 + __ffsll((unsigned long long)m) - 1;
            cnt += __popcll(m);
        }
        if (lane >= cnt && lane < 32) idxs[wv * 32 + lane] = firstj;
    }
    __syncthreads();

    // P1a: gather point features -> cols 0..63
    {
        int r = tid >> 2, seg = tid & 3;
        int j = idxs[r] & 4095;
        size_t off = (base + (size_t)j) * 64 + seg * 16;
        unsigned short* dst = &a1s[r * 200 + seg * 16];
        if (F32) {
            const float* src = (const float*)pf + off;
            #pragma unroll
            for (int q = 0; q < 16; ++q) dst[q] = f2bf(src[q]);
        } else {
            const unsigned short* src = (const unsigned short*)pf + off;
            *(bf16x8*)dst       = *(const bf16x8*)src;
            *(bf16x8*)(dst + 8) = *(const bf16x8*)(src + 8);
        }
    }
    // P1b: rel xyz (64..66) + rel sin-emb 24 (67..90) + zero pad (187..191)
    {
        int r = tid & 63, part = tid >> 6;
        int p = r >> 5;
        int j = idxs[r] & 4095;
        float rx = ldE<F32>(xyz, xbase + (size_t)j * 3 + 0) - ctr[p][0];
        float ry = ldE<F32>(xyz, xbase + (size_t)j * 3 + 1) - ctr[p][1];
        float rz = ldE<F32>(xyz, xbase + (size_t)j * 3 + 2) - ctr[p][2];
        unsigned short* arow = &a1s[r * 200];
        if (part == 0) {
            arow[64] = f2bf(rx); arow[65] = f2bf(ry); arow[66] = f2bf(rz);
            arow[187] = 0; arow[188] = 0; arow[189] = 0; arow[190] = 0; arow[191] = 0;
        } else {
            int a = part - 1;
            float cv = (a == 0) ? rx : ((a == 1) ? ry : rz);
            const float fr4[4] = {1.f, 0.046415888336127774f,
                                  0.0021544346900318843f, 1e-4f};
            #pragma unroll
            for (int tt = 0; tt < 4; ++tt) {
                float ang = cv * fr4[tt];
                arow[67 + a * 8 + tt]     = f2bf(sinf(ang));
                arow[67 + a * 8 + 4 + tt] = f2bf(cosf(ang));
            }
        }
    }
    // P1c: abs emb -> cols 91..186
    #pragma unroll
    for (int it = 0; it < 24; ++it) {
        int v = it * 256 + tid;
        int r = v / 96, cc = v - r * 96;
        a1s[r * 200 + 91 + cc] = f2bf(embs[r >> 5][cc]);
    }
    __syncthreads();

    // P2: C-init = b1; stage-1 MFMA K=192
    f32x4 acc[4][4];
    {
        float b1f[4];
        #pragma unroll
        for (int nt = 0; nt < 4; ++nt)
            b1f[nt] = ldE<F32>(b1, wv * 64 + nt * 16 + lo16);
        #pragma unroll
        for (int mt = 0; mt < 4; ++mt)
            #pragma unroll
            for (int nt = 0; nt < 4; ++nt)
                #pragma unroll
                for (int reg = 0; reg < 4; ++reg) acc[mt][nt][reg] = b1f[nt];
    }
    for (int ks = 0; ks < 6; ++ks) {
        bf16x8 bfr[4];
        #pragma unroll
        for (int nt = 0; nt < 4; ++nt) {
            int n = wv * 64 + nt * 16 + lo16;
            bfr[nt] = *(const bf16x8*)&w1T[n * 192 + ks * 32 + quad * 8];
        }
        #pragma unroll
        for (int mt = 0; mt < 4; ++mt) {
            bf16x8 afr = *(const bf16x8*)&a1s[(mt * 16 + lo16) * 200 + ks * 32 + quad * 8];
            #pragma unroll
            for (int nt = 0; nt < 4; ++nt)
                acc[mt][nt] = __builtin_amdgcn_mfma_f32_16x16x32_bf16(
                    afr, bfr[nt], acc[mt][nt], 0, 0, 0);
        }
    }

    // P3: LN1 -> gelu -> h1s
    #pragma unroll
    for (int mt = 0; mt < 4; ++mt) {
        #pragma unroll
        for (int reg = 0; reg < 4; ++reg) {
            float s1 = 0.f, s2 = 0.f;
            #pragma unroll
            for (int nt = 0; nt < 4; ++nt) { float v = acc[mt][nt][reg]; s1 += v; s2 += v * v; }
            #pragma unroll
            for (int m_ = 1; m_ <= 8; m_ <<= 1) { s1 += __shfl_xor(s1, m_); s2 += __shfl_xor(s2, m_); }
            if (lo16 == 0) { int r = mt * 16 + quad * 4 + reg; reds[r][wv][0] = s1; reds[r][wv][1] = s2; }
        }
    }
    __syncthreads();
    if (tid < 64) {
        int r = tid;
        float s1 = reds[r][0][0] + reds[r][1][0] + reds[r][2][0] + reds[r][3][0];
        float s2 = reds[r][0][1] + reds[r][1][1] + reds[r][2][1] + reds[r][3][1];
        float mu = s1 * (1.f / 256.f);
        float var = fmaxf(s2 * (1.f / 256.f) - mu * mu, 0.f);
        musig[r][0] = mu; musig[r][1] = rsqrtf(var + LN_EPS);
    }
    __syncthreads();
    {
        float g1f[4], be1f[4];
        #pragma unroll
        for (int nt = 0; nt < 4; ++nt) {
            int n = wv * 64 + nt * 16 + lo16;
            g1f[nt] = ldE<F32>(g1, n); be1f[nt] = ldE<F32>(be1, n);
        }
        #pragma unroll
        for (int mt = 0; mt < 4; ++mt) {
            #pragma unroll
            for (int reg = 0; reg < 4; ++reg) {
                int r = mt * 16 + quad * 4 + reg;
                float mu = musig[r][0], rs = musig[r][1];
                #pragma unroll
                for (int nt = 0; nt < 4; ++nt) {
                    float v = (acc[mt][nt][reg] - mu) * rs * g1f[nt] + be1f[nt];
                    h1s[r * 264 + wv * 64 + nt * 16 + lo16] = f2bf(gelu_exact(v));
                }
            }
        }
    }
    __syncthreads();

    // P4: stage-2 MFMA K=256
    #pragma unroll
    for (int mt = 0; mt < 4; ++mt)
        #pragma unroll
        for (int nt = 0; nt < 4; ++nt) acc[mt][nt] = (f32x4){0.f, 0.f, 0.f, 0.f};
    for (int ks = 0; ks < 8; ++ks) {
        bf16x8 bfr[4], afr[4];
        #pragma unroll
        for (int nt = 0; nt < 4; ++nt) {
            int n = wv * 64 + nt * 16 + lo16;
            bfr[nt] = *(const bf16x8*)&w2T[n * 256 + ks * 32 + quad * 8];
        }
        #pragma unroll
        for (int mt = 0; mt < 4; ++mt)
            afr[mt] = *(const bf16x8*)&h1s[(mt * 16 + lo16) * 264 + ks * 32 + quad * 8];
        #pragma unroll
        for (int mt = 0; mt < 4; ++mt)
            #pragma unroll
            for (int nt = 0; nt < 4; ++nt)
                acc[mt][nt] = __builtin_amdgcn_mfma_f32_16x16x32_bf16(
                    afr[mt], bfr[nt], acc[mt][nt], 0, 0, 0);
    }

    // P5: +b2, LN2, row-max -> atomicMax
    {
        float b2f[4], g2f[4], be2f[4];
        #pragma unroll
        for (int nt = 0; nt < 4; ++nt) {
            int n = wv * 64 + nt * 16 + lo16;
            b2f[nt] = ldE<F32>(b2, n); g2f[nt] = ldE<F32>(g2, n); be2f[nt] = ldE<F32>(be2, n);
        }
        #pragma unroll
        for (int mt = 0; mt < 4; ++mt)
            #pragma unroll
            for (int nt = 0; nt < 4; ++nt)
                #pragma unroll
                for (int reg = 0; reg < 4; ++reg) acc[mt][nt][reg] += b2f[nt];

        #pragma unroll
        for (int mt = 0; mt < 4; ++mt) {
            #pragma unroll
            for (int reg = 0; reg < 4; ++reg) {
                float s1 = 0.f, s2 = 0.f;
                #pragma unroll
                for (int nt = 0; nt < 4; ++nt) { float v = acc[mt][nt][reg]; s1 += v; s2 += v * v; }
                #pragma unroll
                for (int m_ = 1; m_ <= 8; m_ <<= 1) { s1 += __shfl_xor(s1, m_); s2 += __shfl_xor(s2, m_); }
                if (lo16 == 0) { int r = mt * 16 + quad * 4 + reg; reds[r][wv][0] = s1; reds[r][wv][1] = s2; }
            }
        }
        __syncthreads();
        if (tid < 64) {
            int r = tid;
            float s1 = reds[r][0][0] + reds[r][1][0] + reds[r][2][0] + reds[r][3][0];
            float s2 = reds[r][0][1] + reds[r][1][1] + reds[r][2][1] + reds[r][3][1];
            float mu = s1 * (1.f / 256.f);
            float var = fmaxf(s2 * (1.f / 256.f) - mu * mu, 0.f);
            musig[r][0] = mu; musig[r][1] = rsqrtf(var + LN_EPS);
        }
        __syncthreads();

        float mx[4] = {-1e30f, -1e30f, -1e30f, -1e30f};
        #pragma unroll
        for (int mt = 0; mt < 4; ++mt) {
            #pragma unroll
            for (int reg = 0; reg < 4; ++reg) {
                int r = mt * 16 + quad * 4 + reg;
                float mu = musig[r][0], rs = musig[r][1];
                #pragma unroll
                for (int nt = 0; nt < 4; ++nt) {
                    float v = (acc[mt][nt][reg] - mu) * rs * g2f[nt] + be2f[nt];
                    mx[nt] = fmaxf(mx[nt], v);
                }
            }
        }
        #pragma unroll
        for (int nt = 0; nt < 4; ++nt) {
            mx[nt] = fmaxf(mx[nt], __shfl_xor(mx[nt], 16));
            mx[nt] = fmaxf(mx[nt], __shfl_xor(mx[nt], 32));
        }
        if (quad == 0) {
            #pragma unroll
            for (int nt = 0; nt < 4; ++nt)
                atomicMax(pooled + b * 256 + wv * 64 + nt * 16 + lo16, fenc(mx[nt]));
        }
    }
}
__global__ __launch_bounds__(256) void k_main(
    const void* xyz, const void* pf,
    const unsigned short* __restrict__ w1T, const unsigned short* __restrict__ w2T,
    const void* b1, const void* g1, const void* be1,
    const void* b2, const void* g2, const void* be2,
    unsigned int* __restrict__ pooled, const int* __restrict__ flag)
{
    if (*flag) main_body<true >(xyz, pf, w1T, w2T, b1, g1, be1, b2, g2, be2, pooled);
    else       main_body<false>(xyz, pf, w1T, w2T, b1, g1, be1, b2, g2, be2, pooled);
}

// ---------------- K_final: two tiny MLPs on pooled [4,256] -----------------
template<bool F32>
__device__ __forceinline__ void final_body(
    const unsigned int* __restrict__ pooled,
    const void* pw1, const void* pb1, const void* pg1, const void* pbe1,
    const void* pw2, const void* pb2, const void* pg2, const void* pbe2,
    void* out)
{
    __shared__ float xb[256];
    __shared__ float red2[8];
    int c = threadIdx.x;
    int b = blockIdx.x;
    xb[c] = fdec(pooled[b * 256 + c]);
    __syncthreads();

    float a = ldE<F32>(pb1, c);
    #pragma unroll 8
    for (int k = 0; k < 256; ++k) a = fmaf(xb[k], ldE<F32>(pw1, (size_t)k * 256 + c), a);
    float s1 = a, s2 = a * a;
    #pragma unroll
    for (int m_ = 1; m_ <= 32; m_ <<= 1) { s1 += __shfl_xor(s1, m_); s2 += __shfl_xor(s2, m_); }
    if ((c & 63) == 0) { red2[(c >> 6) * 2] = s1; red2[(c >> 6) * 2 + 1] = s2; }
    __syncthreads();
    s1 = red2[0] + red2[2] + red2[4] + red2[6];
    s2 = red2[1] + red2[3] + red2[5] + red2[7];
    float mu = s1 * (1.f / 256.f);
    float rs = rsqrtf(fmaxf(s2 * (1.f / 256.f) - mu * mu, 0.f) + LN_EPS);
    float h = gelu_exact((a - mu) * rs * ldE<F32>(pg1, c) + ldE<F32>(pbe1, c));
    __syncthreads();
    xb[c] = h;
    __syncthreads();

    float a2 = ldE<F32>(pb2, c);
    #pragma unroll 8
    for (int k = 0; k < 256; ++k) a2 = fmaf(xb[k], ldE<F32>(pw2, (size_t)k * 256 + c), a2);
    s1 = a2; s2 = a2 * a2;
    #pragma unroll
    for (int m_ = 1; m_ <= 32; m_ <<= 1) { s1 += __shfl_xor(s1, m_); s2 += __shfl_xor(s2, m_); }
    if ((c & 63) == 0) { red2[(c >> 6) * 2] = s1; red2[(c >> 6) * 2 + 1] = s2; }
    __syncthreads();
    s1 = red2[0] + red2[2] + red2[4] + red2[6];
    s2 = red2[1] + red2[3] + red2[5] + red2[7];
    mu = s1 * (1.f / 256.f);
    rs = rsqrtf(fmaxf(s2 * (1.f / 256.f) - mu * mu, 0.f) + LN_EPS);
    float o = (a2 - mu) * rs * ldE<F32>(pg2, c) + ldE<F32>(pbe2, c);
    if (F32) ((float*)out)[b * 256 + c] = o;
    else     ((unsigned short*)out)[b * 256 + c] = f2bf(o);
}
__global__ __launch_bounds__(256) void k_final(
    const unsigned int* __restrict__ pooled,
    const void* pw1, const void* pb1, const void* pg1, const void* pbe1,
    const void* pw2, const void* pb2, const void* pg2, const void* pbe2,
    void* out, const int* __restrict__ flag)
{
    if (*flag) final_body<true >(pooled, pw1, pb1, pg1, pbe1, pw2, pb2, pg2, pbe2, out);
    else       final_body<false>(pooled, pw1, pb1, pg1, pbe1, pw2, pb2, pg2, pbe2, out);
}

// ---------------- launch ---------------------------------------------------
extern "C" void kernel_launch(void* const* d_in, const int* in_sizes, int n_in,
                              void* d_out, int out_size, void* d_ws, size_t ws_size,
                              hipStream_t stream)
{
    char* ws = (char*)d_ws;
    unsigned short* w2T    = (unsigned short*)ws;                      // 128 KB
    unsigned short* w1T    = (unsigned short*)(ws + (128u << 10));     // 96 KB
    unsigned int*   pooled = (unsigned int*)(ws + (224u << 10));       // 4 KB
    int*            flag   = (int*)(ws + (228u << 10));                // 4 B

    k_probe<<<1, 64, 0, stream>>>((const unsigned short*)d_in[0], flag);
    k_prep<<<17, 256, 0, stream>>>(d_in[2], d_in[6], w2T, w1T, pooled, flag);
    k_main<<<8192, 256, 0, stream>>>(d_in[0], d_in[1], w1T, w2T,
                                     d_in[3], d_in[4], d_in[5],
                                     d_in[7], d_in[8], d_in[9], pooled, flag);
    k_final<<<4, 256, 0, stream>>>(pooled,
                                   d_in[10], d_in[11], d_in[12], d_in[13],
                                   d_in[14], d_in[15], d_in[16], d_in[17],
                                   d_out, flag);
}

// Round 4
// 634.463 us; speedup vs baseline: 2.0919x; 2.0919x over previous
//
#include <hip/hip_runtime.h>
#include <math.h>

// GlobalSceneTokenizer fused pipeline, f32 inputs/outputs (confirmed R3).
// pooled[b,c] = max_{i,k} LN2(gelu(LN1(gin@w1+b1))@w2+b2)[c]; final 2 MLPs on [4,256].
// R4: occupancy attack — single f32 path (template dup doubled LDS to 123 KB -> 1 blk/CU),
//     a1s/h1s LDS union (37 KB total -> 4 blk/CU), __launch_bounds__(256,4) VGPR cap.

#define LN_EPS 1e-5f

typedef __attribute__((ext_vector_type(8))) short bf16x8;
typedef __attribute__((ext_vector_type(4))) float f32x4;

__device__ __forceinline__ unsigned short f2bf(float f) {
    unsigned int x = __float_as_uint(f);
    return (unsigned short)((x + 0x7FFFu + ((x >> 16) & 1u)) >> 16);  // RNE
}
__device__ __forceinline__ unsigned int fenc(float f) {
    unsigned int u = __float_as_uint(f);
    return (u & 0x80000000u) ? ~u : (u | 0x80000000u);
}
__device__ __forceinline__ float fdec(unsigned int u) {
    return __uint_as_float((u & 0x80000000u) ? (u & 0x7FFFFFFFu) : ~u);
}
__device__ __forceinline__ float gelu_exact(float x) {
    return 0.5f * x * (1.0f + erff(x * 0.70710678118654752440f));
}

// ---------------- K_prep: w2T, w1T (K-pad 192), pooled init ----------------
__global__ __launch_bounds__(256) void k_prep(
    const float* __restrict__ w1, const float* __restrict__ w2,
    unsigned short* __restrict__ w2T, unsigned short* __restrict__ w1T,
    unsigned int* __restrict__ pooled)
{
    int t = threadIdx.x;
    if (blockIdx.x == 16) {
        for (int k = 0; k < 192; ++k)
            w1T[t * 192 + k] = (k < 187) ? f2bf(w1[(size_t)k * 256 + t])
                                         : (unsigned short)0;
        unsigned int idv = fenc(-1e19f);
        for (int q = t; q < 1024; q += 256) pooled[q] = idv;
        return;
    }
    __shared__ unsigned short tile[64][65];
    int tr = blockIdx.x >> 2, tc = blockIdx.x & 3;
    #pragma unroll
    for (int rr = 0; rr < 16; ++rr) {
        int kl = rr * 4 + (t >> 6), nl = t & 63;
        tile[kl][nl] = f2bf(w2[(size_t)(tr * 64 + kl) * 256 + tc * 64 + nl]);
    }
    __syncthreads();
    #pragma unroll
    for (int rr = 0; rr < 16; ++rr) {
        int nl = rr * 4 + (t >> 6), kl = t & 63;
        w2T[(tc * 64 + nl) * 256 + tr * 64 + kl] = tile[kl][nl];
    }
}

// ---------------- K_main ---------------------------------------------------
__global__ __launch_bounds__(256, 4) void k_main(
    const float* __restrict__ xyz, const float* __restrict__ pf,
    const unsigned short* __restrict__ w1T, const unsigned short* __restrict__ w2T,
    const float* __restrict__ b1, const float* __restrict__ g1,
    const float* __restrict__ be1,
    const float* __restrict__ b2, const float* __restrict__ g2,
    const float* __restrict__ be2,
    unsigned int* __restrict__ pooled)
{
    // a1s (64 x 192+8pad) and h1s (64 x 256+8pad) share one buffer:
    // a1s dead after stage-1 MFMA; two barriers separate last a1s read
    // from first h1s write.
    __shared__ __align__(16) unsigned short smem[64 * 264];   // 33.8 KB
    __shared__ float embs[2][96];
    __shared__ float reds[64][4][2];
    __shared__ float musig[64][2];
    __shared__ int   idxs[64];
    __shared__ float ctr[2][3];
    unsigned short* a1s = smem;   // stride 200
    unsigned short* h1s = smem;   // stride 264

    const int N = 4096;
    int tid = threadIdx.x, wv = tid >> 6, lane = tid & 63;
    int lo16 = lane & 15, quad = lane >> 4;
    int b = blockIdx.x & 3;                    // batch-major for L2 locality
    int i0 = (blockIdx.x >> 2) * 2;
    size_t base = (size_t)b * N;
    const float* xb = xyz + base * 3;

    // P0a: centers
    if (tid < 6) { int p = tid / 3, a = tid - 3 * p; ctr[p][a] = xb[(i0 + p) * 3 + a]; }
    // P0b: abs sin-emb (dim 96) for both centers
    if (tid < 192) {
        int p = (tid >= 96) ? 1 : 0, cc = tid - 96 * p;
        int a = cc >> 5, wI = cc & 31;
        int jf = (wI < 16) ? wI : (wI - 16);
        float coord = xb[(i0 + p) * 3 + a];
        float fr = expf(-9.210340371976184f * (float)jf * (1.f / 15.f)); // 10000^(-jf/15)
        float ang = coord * fr;
        embs[p][cc] = (wI < 16) ? sinf(ang) : cosf(ang);
    }
    // P0c: ball query (waves 0/1): first 32 in-ball by ascending index
    if (wv < 2) {
        int i = i0 + wv;
        float cx = xb[i * 3], cy = xb[i * 3 + 1], cz = xb[i * 3 + 2];
        int cnt = 0, firstj = -1;
        for (int c0 = 0; c0 < N && cnt < 32; c0 += 64) {
            int j = c0 + lane;
            float dx = __fsub_rn(xb[j * 3], cx);
            float dy = __fsub_rn(xb[j * 3 + 1], cy);
            float dz = __fsub_rn(xb[j * 3 + 2], cz);
            float sq = __fadd_rn(__fadd_rn(__fmul_rn(dx, dx), __fmul_rn(dy, dy)),
                                 __fmul_rn(dz, dz));
            bool inball = !((double)sq > (double)0.16 * 0.16);  // numpy promotion
            unsigned long long m = __ballot(inball);
            int rank = __popcll(m & ((1ull << lane) - 1ull));
            if (inball && (cnt + rank) < 32) idxs[wv * 32 + cnt + rank] = j;
            if (firstj < 0 && m != 0ull) firstj = c0 + __ffsll((unsigned long long)m) - 1;
            cnt += __popcll(m);
        }
        if (lane >= cnt && lane < 32) idxs[wv * 32 + lane] = firstj;
    }
    __syncthreads();

    // P1a: gather point features -> cols 0..63 (float4 loads)
    {
        int r = tid >> 2, seg = tid & 3;
        int j = idxs[r] & 4095;
        const f32x4* src = (const f32x4*)(pf + (base + (size_t)j) * 64 + seg * 16);
        unsigned short* dst = &a1s[r * 200 + seg * 16];
        #pragma unroll
        for (int q = 0; q < 4; ++q) {
            f32x4 v = src[q];
            dst[q * 4 + 0] = f2bf(v.x); dst[q * 4 + 1] = f2bf(v.y);
            dst[q * 4 + 2] = f2bf(v.z); dst[q * 4 + 3] = f2bf(v.w);
        }
    }
    // P1b: rel xyz (64..66) + rel sin-emb 24 (67..90) + zero pad (187..191)
    {
        int r = tid & 63, part = tid >> 6;
        int p = r >> 5;
        int j = idxs[r] & 4095;
        float rx = xb[j * 3]     - ctr[p][0];
        float ry = xb[j * 3 + 1] - ctr[p][1];
        float rz = xb[j * 3 + 2] - ctr[p][2];
        unsigned short* arow = &a1s[r * 200];
        if (part == 0) {
            arow[64] = f2bf(rx); arow[65] = f2bf(ry); arow[66] = f2bf(rz);
            arow[187] = 0; arow[188] = 0; arow[189] = 0; arow[190] = 0; arow[191] = 0;
        } else {
            int a = part - 1;
            float cv = (a == 0) ? rx : ((a == 1) ? ry : rz);
            const float fr4[4] = {1.f, 0.046415888336127774f,
                                  0.0021544346900318843f, 1e-4f};  // 10000^(-j/3)
            #pragma unroll
            for (int tt = 0; tt < 4; ++tt) {
                float ang = cv * fr4[tt];
                arow[67 + a * 8 + tt]     = f2bf(sinf(ang));
                arow[67 + a * 8 + 4 + tt] = f2bf(cosf(ang));
            }
        }
    }
    // P1c: abs emb -> cols 91..186
    #pragma unroll
    for (int it = 0; it < 24; ++it) {
        int v = it * 256 + tid;                 // 24*256 == 64*96
        int r = v / 96, cc = v - r * 96;
        a1s[r * 200 + 91 + cc] = f2bf(embs[r >> 5][cc]);
    }
    __syncthreads();

    // P2: C-init = b1; stage-1 MFMA K=192
    f32x4 acc[4][4];
    {
        float b1f[4];
        #pragma unroll
        for (int nt = 0; nt < 4; ++nt) b1f[nt] = b1[wv * 64 + nt * 16 + lo16];
        #pragma unroll
        for (int mt = 0; mt < 4; ++mt)
            #pragma unroll
            for (int nt = 0; nt < 4; ++nt)
                #pragma unroll
                for (int reg = 0; reg < 4; ++reg) acc[mt][nt][reg] = b1f[nt];
    }
    for (int ks = 0; ks < 6; ++ks) {
        bf16x8 bfr[4];
        #pragma unroll
        for (int nt = 0; nt < 4; ++nt) {
            int n = wv * 64 + nt * 16 + lo16;
            bfr[nt] = *(const bf16x8*)&w1T[n * 192 + ks * 32 + quad * 8];
        }
        #pragma unroll
        for (int mt = 0; mt < 4; ++mt) {
            bf16x8 afr = *(const bf16x8*)&a1s[(mt * 16 + lo16) * 200 + ks * 32 + quad * 8];
            #pragma unroll
            for (int nt = 0; nt < 4; ++nt)
                acc[mt][nt] = __builtin_amdgcn_mfma_f32_16x16x32_bf16(
                    afr, bfr[nt], acc[mt][nt], 0, 0, 0);
        }
    }

    // P3: LN1 stats -> gelu -> h1s
    #pragma unroll
    for (int mt = 0; mt < 4; ++mt) {
        #pragma unroll
        for (int reg = 0; reg < 4; ++reg) {
            float s1 = 0.f, s2 = 0.f;
            #pragma unroll
            for (int nt = 0; nt < 4; ++nt) { float v = acc[mt][nt][reg]; s1 += v; s2 += v * v; }
            #pragma unroll
            for (int m_ = 1; m_ <= 8; m_ <<= 1) { s1 += __shfl_xor(s1, m_); s2 += __shfl_xor(s2, m_); }
            if (lo16 == 0) { int r = mt * 16 + quad * 4 + reg; reds[r][wv][0] = s1; reds[r][wv][1] = s2; }
        }
    }
    __syncthreads();   // reds ready; also: all waves done reading a1s
    if (tid < 64) {
        int r = tid;
        float s1 = reds[r][0][0] + reds[r][1][0] + reds[r][2][0] + reds[r][3][0];
        float s2 = reds[r][0][1] + reds[r][1][1] + reds[r][2][1] + reds[r][3][1];
        float mu = s1 * (1.f / 256.f);
        float var = fmaxf(s2 * (1.f / 256.f) - mu * mu, 0.f);
        musig[r][0] = mu; musig[r][1] = rsqrtf(var + LN_EPS);
    }
    __syncthreads();
    {
        float g1f[4], be1f[4];
        #pragma unroll
        for (int nt = 0; nt < 4; ++nt) {
            int n = wv * 64 + nt * 16 + lo16;
            g1f[nt] = g1[n]; be1f[nt] = be1[n];
        }
        #pragma unroll
        for (int mt = 0; mt < 4; ++mt) {
            #pragma unroll
            for (int reg = 0; reg < 4; ++reg) {
                int r = mt * 16 + quad * 4 + reg;
                float mu = musig[r][0], rs = musig[r][1];
                #pragma unroll
                for (int nt = 0; nt < 4; ++nt) {
                    float v = (acc[mt][nt][reg] - mu) * rs * g1f[nt] + be1f[nt];
                    h1s[r * 264 + wv * 64 + nt * 16 + lo16] = f2bf(gelu_exact(v));
                }
            }
        }
    }
    __syncthreads();   // h1s ready

    // P4: stage-2 MFMA K=256
    #pragma unroll
    for (int mt = 0; mt < 4; ++mt)
        #pragma unroll
        for (int nt = 0; nt < 4; ++nt) acc[mt][nt] = (f32x4){0.f, 0.f, 0.f, 0.f};
    for (int ks = 0; ks < 8; ++ks) {
        bf16x8 bfr[4], afr[4];
        #pragma unroll
        for (int nt = 0; nt < 4; ++nt) {
            int n = wv * 64 + nt * 16 + lo16;
            bfr[nt] = *(const bf16x8*)&w2T[n * 256 + ks * 32 + quad * 8];
        }
        #pragma unroll
        for (int mt = 0; mt < 4; ++mt)
            afr[mt] = *(const bf16x8*)&h1s[(mt * 16 + lo16) * 264 + ks * 32 + quad * 8];
        #pragma unroll
        for (int mt = 0; mt < 4; ++mt)
            #pragma unroll
            for (int nt = 0; nt < 4; ++nt)
                acc[mt][nt] = __builtin_amdgcn_mfma_f32_16x16x32_bf16(
                    afr[mt], bfr[nt], acc[mt][nt], 0, 0, 0);
    }

    // P5: +b2, LN2, row-max -> atomicMax
    {
        float b2f[4], g2f[4], be2f[4];
        #pragma unroll
        for (int nt = 0; nt < 4; ++nt) {
            int n = wv * 64 + nt * 16 + lo16;
            b2f[nt] = b2[n]; g2f[nt] = g2[n]; be2f[nt] = be2[n];
        }
        #pragma unroll
        for (int mt = 0; mt < 4; ++mt)
            #pragma unroll
            for (int nt = 0; nt < 4; ++nt)
                #pragma unroll
                for (int reg = 0; reg < 4; ++reg) acc[mt][nt][reg] += b2f[nt];

        #pragma unroll
        for (int mt = 0; mt < 4; ++mt) {
            #pragma unroll
            for (int reg = 0; reg < 4; ++reg) {
                float s1 = 0.f, s2 = 0.f;
                #pragma unroll
                for (int nt = 0; nt < 4; ++nt) { float v = acc[mt][nt][reg]; s1 += v; s2 += v * v; }
                #pragma unroll
                for (int m_ = 1; m_ <= 8; m_ <<= 1) { s1 += __shfl_xor(s1, m_); s2 += __shfl_xor(s2, m_); }
                if (lo16 == 0) { int r = mt * 16 + quad * 4 + reg; reds[r][wv][0] = s1; reds[r][wv][1] = s2; }
            }
        }
        __syncthreads();
        if (tid < 64) {
            int r = tid;
            float s1 = reds[r][0][0] + reds[r][1][0] + reds[r][2][0] + reds[r][3][0];
            float s2 = reds[r][0][1] + reds[r][1][1] + reds[r][2][1] + reds[r][3][1];
            float mu = s1 * (1.f / 256.f);
            float var = fmaxf(s2 * (1.f / 256.f) - mu * mu, 0.f);
            musig[r][0] = mu; musig[r][1] = rsqrtf(var + LN_EPS);
        }
        __syncthreads();

        float mx[4] = {-1e30f, -1e30f, -1e30f, -1e30f};
        #pragma unroll
        for (int mt = 0; mt < 4; ++mt) {
            #pragma unroll
            for (int reg = 0; reg < 4; ++reg) {
                int r = mt * 16 + quad * 4 + reg;
                float mu = musig[r][0], rs = musig[r][1];
                #pragma unroll
                for (int nt = 0; nt < 4; ++nt) {
                    float v = (acc[mt][nt][reg] - mu) * rs * g2f[nt] + be2f[nt];
                    mx[nt] = fmaxf(mx[nt], v);
                }
            }
        }
        #pragma unroll
        for (int nt = 0; nt < 4; ++nt) {
            mx[nt] = fmaxf(mx[nt], __shfl_xor(mx[nt], 16));
            mx[nt] = fmaxf(mx[nt], __shfl_xor(mx[nt], 32));
        }
        if (quad == 0) {
            #pragma unroll
            for (int nt = 0; nt < 4; ++nt)
                atomicMax(pooled + b * 256 + wv * 64 + nt * 16 + lo16, fenc(mx[nt]));
        }
    }
}

// ---------------- K_final: two tiny MLPs on pooled [4,256] -----------------
__global__ __launch_bounds__(256) void k_final(
    const unsigned int* __restrict__ pooled,
    const float* __restrict__ pw1, const float* __restrict__ pb1,
    const float* __restrict__ pg1, const float* __restrict__ pbe1,
    const float* __restrict__ pw2, const float* __restrict__ pb2,
    const float* __restrict__ pg2, const float* __restrict__ pbe2,
    float* __restrict__ out)
{
    __shared__ float xb[256];
    __shared__ float red2[8];
    int c = threadIdx.x;
    int b = blockIdx.x;
    xb[c] = fdec(pooled[b * 256 + c]);
    __syncthreads();

    float a = pb1[c];
    #pragma unroll 8
    for (int k = 0; k < 256; ++k) a = fmaf(xb[k], pw1[(size_t)k * 256 + c], a);
    float s1 = a, s2 = a * a;
    #pragma unroll
    for (int m_ = 1; m_ <= 32; m_ <<= 1) { s1 += __shfl_xor(s1, m_); s2 += __shfl_xor(s2, m_); }
    if ((c & 63) == 0) { red2[(c >> 6) * 2] = s1; red2[(c >> 6) * 2 + 1] = s2; }
    __syncthreads();
    s1 = red2[0] + red2[2] + red2[4] + red2[6];
    s2 = red2[1] + red2[3] + red2[5] + red2[7];
    float mu = s1 * (1.f / 256.f);
    float rs = rsqrtf(fmaxf(s2 * (1.f / 256.f) - mu * mu, 0.f) + LN_EPS);
    float h = gelu_exact((a - mu) * rs * pg1[c] + pbe1[c]);
    __syncthreads();
    xb[c] = h;
    __syncthreads();

    float a2 = pb2[c];
    #pragma unroll 8
    for (int k = 0; k < 256; ++k) a2 = fmaf(xb[k], pw2[(size_t)k * 256 + c], a2);
    s1 = a2; s2 = a2 * a2;
    #pragma unroll
    for (int m_ = 1; m_ <= 32; m_ <<= 1) { s1 += __shfl_xor(s1, m_); s2 += __shfl_xor(s2, m_); }
    if ((c & 63) == 0) { red2[(c >> 6) * 2] = s1; red2[(c >> 6) * 2 + 1] = s2; }
    __syncthreads();
    s1 = red2[0] + red2[2] + red2[4] + red2[6];
    s2 = red2[1] + red2[3] + red2[5] + red2[7];
    mu = s1 * (1.f / 256.f);
    rs = rsqrtf(fmaxf(s2 * (1.f / 256.f) - mu * mu, 0.f) + LN_EPS);
    out[b * 256 + c] = (a2 - mu) * rs * pg2[c] + pbe2[c];
}

// ---------------- launch ---------------------------------------------------
extern "C" void kernel_launch(void* const* d_in, const int* in_sizes, int n_in,
                              void* d_out, int out_size, void* d_ws, size_t ws_size,
                              hipStream_t stream)
{
    char* ws = (char*)d_ws;
    unsigned short* w2T    = (unsigned short*)ws;                      // 128 KB
    unsigned short* w1T    = (unsigned short*)(ws + (128u << 10));     // 96 KB
    unsigned int*   pooled = (unsigned int*)(ws + (224u << 10));       // 4 KB

    k_prep<<<17, 256, 0, stream>>>((const float*)d_in[2], (const float*)d_in[6],
                                   w2T, w1T, pooled);
    k_main<<<8192, 256, 0, stream>>>((const float*)d_in[0], (const float*)d_in[1],
                                     w1T, w2T,
                                     (const float*)d_in[3], (const float*)d_in[4],
                                     (const float*)d_in[5],
                                     (const float*)d_in[7], (const float*)d_in[8],
                                     (const float*)d_in[9], pooled);
    k_final<<<4, 256, 0, stream>>>(pooled,
                                   (const float*)d_in[10], (const float*)d_in[11],
                                   (const float*)d_in[12], (const float*)d_in[13],
                                   (const float*)d_in[14], (const float*)d_in[15],
                                   (const float*)d_in[16], (const float*)d_in[17],
                                   (float*)d_out);
}

// Round 5
// 490.421 us; speedup vs baseline: 2.7064x; 1.2937x over previous
//
#include <hip/hip_runtime.h>
#include <math.h>

// GlobalSceneTokenizer fused pipeline, f32 in/out (confirmed R3).
// pooled[b,c] = max_{i,k} LN2(gelu(LN1(gin@w1+b1))@w2+b2)[c]; final 2 MLPs on [4,256].
// R5: VALU attack — AS-7.1.26 fast erf gelu, __sinf/__cosf/__expf embeddings,
//     GEMM2 k-permutation so h1 LDS writes are packed b64 (no sub-dword conflicts),
//     packed pf-gather/abs-emb writes, fully-tiled k_prep.
// a1s col map: [0..63]=pf | [64..66]=relxyz | [67..90]=relemb24 | [91]=0 |
//              [92..187]=absemb96 | [188..191]=0   (w1T rows remapped to match)

#define LN_EPS 1e-5f

typedef __attribute__((ext_vector_type(8))) short bf16x8;
typedef __attribute__((ext_vector_type(4))) float f32x4;
typedef __attribute__((ext_vector_type(2))) unsigned int u32x2;
typedef __attribute__((ext_vector_type(4))) unsigned int u32x4;

#if __has_builtin(__builtin_amdgcn_rcpf)
#define FRCP(x) __builtin_amdgcn_rcpf(x)
#else
#define FRCP(x) (1.0f / (x))
#endif

__device__ __forceinline__ unsigned short f2bf(float f) {
    unsigned int x = __float_as_uint(f);
    return (unsigned short)((x + 0x7FFFu + ((x >> 16) & 1u)) >> 16);  // RNE
}
__device__ __forceinline__ unsigned int pack2(float a, float b) {  // [b|a] bf16x2
    unsigned int ua = __float_as_uint(a), ub = __float_as_uint(b);
    ua = ua + 0x7FFFu + ((ua >> 16) & 1u);
    ub = ub + 0x7FFFu + ((ub >> 16) & 1u);
    return (ua >> 16) | (ub & 0xFFFF0000u);
}
__device__ __forceinline__ unsigned int fenc(float f) {
    unsigned int u = __float_as_uint(f);
    return (u & 0x80000000u) ? ~u : (u | 0x80000000u);
}
__device__ __forceinline__ float fdec(unsigned int u) {
    return __uint_as_float((u & 0x80000000u) ? (u & 0x7FFFFFFFu) : ~u);
}
// gelu exact-shape via Abramowitz-Stegun 7.1.26 erf (|eps|<=1.5e-7), branch-free
__device__ __forceinline__ float gelu_fast(float x) {
    float s = fabsf(x) * 0.70710678118654752f;
    float t = FRCP(fmaf(0.3275911f, s, 1.0f));
    float p = fmaf(fmaf(fmaf(fmaf(1.061405429f, t, -1.453152027f), t,
                             1.421413741f), t, -0.284496736f), t, 0.254829592f) * t;
    float e = __expf(-s * s);
    float E = fmaf(-p, e, 1.0f);                    // erf(|x|/sqrt2)
    return fmaf(0.5f * fabsf(x), E, 0.5f * x);      // 0.5x + 0.5|x|erf
}

// ---------------- K_prep: w2T (k-permuted), w1T (col-91-shift), pooled init
// GEMM2 k-permutation: pi(k) within each 64-block: pi(nt*16+lo) = lo*4+nt.
__global__ __launch_bounds__(256) void k_prep(
    const float* __restrict__ w1, const float* __restrict__ w2,
    unsigned short* __restrict__ w2T, unsigned short* __restrict__ w1T,
    unsigned int* __restrict__ pooled)
{
    int t = threadIdx.x, blk = blockIdx.x;
    if (blk < 16) {                      // w2T: [n=256][k=256 permuted]
        __shared__ unsigned short tile[64][65];
        int tr = blk >> 2, tc = blk & 3;     // k-tile, n-tile
        #pragma unroll
        for (int rr = 0; rr < 16; ++rr) {
            int kl = rr * 4 + (t >> 6), nl = t & 63;
            tile[kl][nl] = f2bf(w2[(size_t)(tr * 64 + kl) * 256 + tc * 64 + nl]);
        }
        __syncthreads();
        #pragma unroll
        for (int rr = 0; rr < 16; ++rr) {
            int nl = rr * 4 + (t >> 6), kp = t & 63;
            int kl = (kp & 3) * 16 + (kp >> 2);      // pi^-1
            w2T[(size_t)(tc * 64 + nl) * 256 + tr * 64 + kp] = tile[kl][nl];
        }
    } else if (blk < 28) {               // w1T: [n=256][k=192], zero col 91 + tail
        __shared__ unsigned short tile[64][65];
        int idx = blk - 16;
        int tr = idx >> 2, tc = idx & 3;     // tr 0..2
        #pragma unroll
        for (int rr = 0; rr < 16; ++rr) {
            int kl = rr * 4 + (t >> 6), nl = t & 63;
            int kp = tr * 64 + kl;
            float v = 0.f;
            if (kp < 91)                       v = w1[(size_t)kp * 256 + tc * 64 + nl];
            else if (kp >= 92 && kp <= 187)    v = w1[(size_t)(kp - 1) * 256 + tc * 64 + nl];
            tile[kl][nl] = f2bf(v);
        }
        __syncthreads();
        #pragma unroll
        for (int rr = 0; rr < 16; ++rr) {
            int nl = rr * 4 + (t >> 6), kl = t & 63;
            w1T[(size_t)(tc * 64 + nl) * 192 + tr * 64 + kl] = tile[kl][nl];
        }
    } else {                             // pooled init
        unsigned int idv = fenc(-1e19f);
        for (int q = t; q < 1024; q += 256) pooled[q] = idv;
    }
}

// ---------------- K_main ---------------------------------------------------
__global__ __launch_bounds__(256, 4) void k_main(
    const float* __restrict__ xyz, const float* __restrict__ pf,
    const unsigned short* __restrict__ w1T, const unsigned short* __restrict__ w2T,
    const float* __restrict__ b1, const float* __restrict__ g1,
    const float* __restrict__ be1,
    const float* __restrict__ b2, const float* __restrict__ g2,
    const float* __restrict__ be2,
    unsigned int* __restrict__ pooled)
{
    // a1s (64 x 192+8, stride 200) unioned with h1s (64 x 256+8, stride 264):
    // a1s dead after stage-1 MFMA; two barriers before first h1s write.
    __shared__ __align__(16) unsigned short smem[64 * 264];   // 33.8 KB
    __shared__ float embs[2][96];
    __shared__ float reds[64][4][2];
    __shared__ float musig[64][2];
    __shared__ int   idxs[64];
    __shared__ float ctr[2][3];
    unsigned short* a1s = smem;   // stride 200
    unsigned short* h1s = smem;   // stride 264 (k-permuted within 64-blocks)

    const int N = 4096;
    int tid = threadIdx.x, wv = tid >> 6, lane = tid & 63;
    int lo16 = lane & 15, quad = lane >> 4;
    int b = blockIdx.x & 3;                    // batch-major for L2 locality
    int i0 = (blockIdx.x >> 2) * 2;
    size_t base = (size_t)b * N;
    const float* xb = xyz + base * 3;

    // P0a: centers
    if (tid < 6) { int p = tid / 3, a = tid - 3 * p; ctr[p][a] = xb[(i0 + p) * 3 + a]; }
    // P0b: abs sin-emb (96) for both centers; freq = 10000^(-jf/15)
    if (tid < 192) {
        int p = (tid >= 96) ? 1 : 0, cc = tid - 96 * p;
        int a = cc >> 5, wI = cc & 31;
        int jf = (wI < 16) ? wI : (wI - 16);
        float coord = xb[(i0 + p) * 3 + a];
        float fr = __expf(-0.61402269146507894f * (float)jf);
        float ang = coord * fr;
        embs[p][cc] = (wI < 16) ? __sinf(ang) : __cosf(ang);
    }
    // P0c: ball query (waves 0/1): first 32 in-ball by ascending index
    if (wv < 2) {
        int i = i0 + wv;
        float cx = xb[i * 3], cy = xb[i * 3 + 1], cz = xb[i * 3 + 2];
        int cnt = 0, firstj = -1;
        for (int c0 = 0; c0 < N && cnt < 32; c0 += 64) {
            int j = c0 + lane;
            float dx = __fsub_rn(xb[j * 3], cx);
            float dy = __fsub_rn(xb[j * 3 + 1], cy);
            float dz = __fsub_rn(xb[j * 3 + 2], cz);
            float sq = __fadd_rn(__fadd_rn(__fmul_rn(dx, dx), __fmul_rn(dy, dy)),
                                 __fmul_rn(dz, dz));
            bool inball = !((double)sq > (double)0.16 * 0.16);  // numpy promotion
            unsigned long long m = __ballot(inball);
            int rank = __popcll(m & ((1ull << lane) - 1ull));
            if (inball && (cnt + rank) < 32) idxs[wv * 32 + cnt + rank] = j;
            if (firstj < 0 && m != 0ull) firstj = c0 + __ffsll((unsigned long long)m) - 1;
            cnt += __popcll(m);
        }
        if (lane >= cnt && lane < 32) idxs[wv * 32 + lane] = firstj;
    }
    __syncthreads();

    // P1a: gather pf -> cols 0..63, packed b128 LDS writes
    {
        int r = tid >> 2, seg = tid & 3;
        int j = idxs[r] & 4095;
        const f32x4* src = (const f32x4*)(pf + (base + (size_t)j) * 64 + seg * 16);
        f32x4 v0 = src[0], v1 = src[1], v2 = src[2], v3 = src[3];
        u32x4 o0, o1;
        o0.x = pack2(v0.x, v0.y); o0.y = pack2(v0.z, v0.w);
        o0.z = pack2(v1.x, v1.y); o0.w = pack2(v1.z, v1.w);
        o1.x = pack2(v2.x, v2.y); o1.y = pack2(v2.z, v2.w);
        o1.z = pack2(v3.x, v3.y); o1.w = pack2(v3.z, v3.w);
        u32x4* dst = (u32x4*)&a1s[r * 200 + seg * 16];
        dst[0] = o0; dst[1] = o1;
    }
    // P1b: rel xyz (64..66) + rel emb (67..90) + zeros (91, 188..191)
    {
        int r = tid & 63, part = tid >> 6;
        int p = r >> 5;
        int j = idxs[r] & 4095;
        float rx = xb[j * 3]     - ctr[p][0];
        float ry = xb[j * 3 + 1] - ctr[p][1];
        float rz = xb[j * 3 + 2] - ctr[p][2];
        unsigned short* arow = &a1s[r * 200];
        if (part == 0) {
            arow[64] = f2bf(rx); arow[65] = f2bf(ry); arow[66] = f2bf(rz);
            arow[91] = 0;
            *(u32x2*)&arow[188] = (u32x2){0u, 0u};
        } else {
            int a = part - 1;
            float cv = (a == 0) ? rx : ((a == 1) ? ry : rz);
            const float fr4[4] = {1.f, 0.046415888336127774f,
                                  0.0021544346900318843f, 1e-4f};  // 10000^(-j/3)
            #pragma unroll
            for (int tt = 0; tt < 4; ++tt) {
                float ang = cv * fr4[tt];
                arow[67 + a * 8 + tt]     = f2bf(__sinf(ang));
                arow[67 + a * 8 + 4 + tt] = f2bf(__cosf(ang));
            }
        }
    }
    // P1c: abs emb -> cols 92..187, packed u32 writes
    {
        int r = tid >> 2, part = tid & 3, p = r >> 5;
        const float* e = embs[p] + part * 24;
        unsigned int* dst = (unsigned int*)&a1s[r * 200 + 92 + part * 24];
        #pragma unroll
        for (int q = 0; q < 12; ++q) dst[q] = pack2(e[2 * q], e[2 * q + 1]);
    }
    __syncthreads();

    // P2: C-init = b1; stage-1 MFMA K=192
    f32x4 acc[4][4];
    {
        float b1f[4];
        #pragma unroll
        for (int nt = 0; nt < 4; ++nt) b1f[nt] = b1[wv * 64 + nt * 16 + lo16];
        #pragma unroll
        for (int mt = 0; mt < 4; ++mt)
            #pragma unroll
            for (int nt = 0; nt < 4; ++nt)
                #pragma unroll
                for (int reg = 0; reg < 4; ++reg) acc[mt][nt][reg] = b1f[nt];
    }
    for (int ks = 0; ks < 6; ++ks) {
        bf16x8 bfr[4];
        #pragma unroll
        for (int nt = 0; nt < 4; ++nt) {
            int n = wv * 64 + nt * 16 + lo16;
            bfr[nt] = *(const bf16x8*)&w1T[n * 192 + ks * 32 + quad * 8];
        }
        #pragma unroll
        for (int mt = 0; mt < 4; ++mt) {
            bf16x8 afr = *(const bf16x8*)&a1s[(mt * 16 + lo16) * 200 + ks * 32 + quad * 8];
            #pragma unroll
            for (int nt = 0; nt < 4; ++nt)
                acc[mt][nt] = __builtin_amdgcn_mfma_f32_16x16x32_bf16(
                    afr, bfr[nt], acc[mt][nt], 0, 0, 0);
        }
    }

    // P3: LN1 stats -> gelu -> h1s (k-permuted packed b64 writes)
    #pragma unroll
    for (int mt = 0; mt < 4; ++mt) {
        #pragma unroll
        for (int reg = 0; reg < 4; ++reg) {
            float s1 = 0.f, s2 = 0.f;
            #pragma unroll
            for (int nt = 0; nt < 4; ++nt) { float v = acc[mt][nt][reg]; s1 += v; s2 += v * v; }
            #pragma unroll
            for (int m_ = 1; m_ <= 8; m_ <<= 1) { s1 += __shfl_xor(s1, m_); s2 += __shfl_xor(s2, m_); }
            if (lo16 == 0) { int r = mt * 16 + quad * 4 + reg; reds[r][wv][0] = s1; reds[r][wv][1] = s2; }
        }
    }
    __syncthreads();   // reds ready; all waves done reading a1s
    if (tid < 64) {
        int r = tid;
        float s1 = reds[r][0][0] + reds[r][1][0] + reds[r][2][0] + reds[r][3][0];
        float s2 = reds[r][0][1] + reds[r][1][1] + reds[r][2][1] + reds[r][3][1];
        float mu = s1 * (1.f / 256.f);
        float var = fmaxf(s2 * (1.f / 256.f) - mu * mu, 0.f);
        musig[r][0] = mu; musig[r][1] = rsqrtf(var + LN_EPS);
    }
    __syncthreads();
    {
        float g1f[4], be1f[4];
        #pragma unroll
        for (int nt = 0; nt < 4; ++nt) {
            int n = wv * 64 + nt * 16 + lo16;
            g1f[nt] = g1[n]; be1f[nt] = be1[n];
        }
        #pragma unroll
        for (int mt = 0; mt < 4; ++mt) {
            #pragma unroll
            for (int reg = 0; reg < 4; ++reg) {
                int r = mt * 16 + quad * 4 + reg;
                float mu = musig[r][0], rs = musig[r][1];
                float v0 = gelu_fast(fmaf((acc[mt][0][reg] - mu) * rs, g1f[0], be1f[0]));
                float v1 = gelu_fast(fmaf((acc[mt][1][reg] - mu) * rs, g1f[1], be1f[1]));
                float v2 = gelu_fast(fmaf((acc[mt][2][reg] - mu) * rs, g1f[2], be1f[2]));
                float v3 = gelu_fast(fmaf((acc[mt][3][reg] - mu) * rs, g1f[3], be1f[3]));
                u32x2 w; w.x = pack2(v0, v1); w.y = pack2(v2, v3);
                *(u32x2*)&h1s[r * 264 + wv * 64 + lo16 * 4] = w;   // pi(n)=lo16*4+nt
            }
        }
    }
    __syncthreads();   // h1s ready

    // P4: stage-2 MFMA K=256 (k-permuted; w2T permuted to match)
    #pragma unroll
    for (int mt = 0; mt < 4; ++mt)
        #pragma unroll
        for (int nt = 0; nt < 4; ++nt) acc[mt][nt] = (f32x4){0.f, 0.f, 0.f, 0.f};
    for (int ks = 0; ks < 8; ++ks) {
        bf16x8 bfr[4], afr[4];
        #pragma unroll
        for (int nt = 0; nt < 4; ++nt) {
            int n = wv * 64 + nt * 16 + lo16;
            bfr[nt] = *(const bf16x8*)&w2T[n * 256 + ks * 32 + quad * 8];
        }
        #pragma unroll
        for (int mt = 0; mt < 4; ++mt)
            afr[mt] = *(const bf16x8*)&h1s[(mt * 16 + lo16) * 264 + ks * 32 + quad * 8];
        #pragma unroll
        for (int mt = 0; mt < 4; ++mt)
            #pragma unroll
            for (int nt = 0; nt < 4; ++nt)
                acc[mt][nt] = __builtin_amdgcn_mfma_f32_16x16x32_bf16(
                    afr[mt], bfr[nt], acc[mt][nt], 0, 0, 0);
    }

    // P5: +b2, LN2, row-max -> atomicMax
    {
        float b2f[4], g2f[4], be2f[4];
        #pragma unroll
        for (int nt = 0; nt < 4; ++nt) {
            int n = wv * 64 + nt * 16 + lo16;
            b2f[nt] = b2[n]; g2f[nt] = g2[n]; be2f[nt] = be2[n];
        }
        #pragma unroll
        for (int mt = 0; mt < 4; ++mt)
            #pragma unroll
            for (int nt = 0; nt < 4; ++nt)
                #pragma unroll
                for (int reg = 0; reg < 4; ++reg) acc[mt][nt][reg] += b2f[nt];

        #pragma unroll
        for (int mt = 0; mt < 4; ++mt) {
            #pragma unroll
            for (int reg = 0; reg < 4; ++reg) {
                float s1 = 0.f, s2 = 0.f;
                #pragma unroll
                for (int nt = 0; nt < 4; ++nt) { float v = acc[mt][nt][reg]; s1 += v; s2 += v * v; }
                #pragma unroll
                for (int m_ = 1; m_ <= 8; m_ <<= 1) { s1 += __shfl_xor(s1, m_); s2 += __shfl_xor(s2, m_); }
                if (lo16 == 0) { int r = mt * 16 + quad * 4 + reg; reds[r][wv][0] = s1; reds[r][wv][1] = s2; }
            }
        }
        __syncthreads();
        if (tid < 64) {
            int r = tid;
            float s1 = reds[r][0][0] + reds[r][1][0] + reds[r][2][0] + reds[r][3][0];
            float s2 = reds[r][0][1] + reds[r][1][1] + reds[r][2][1] + reds[r][3][1];
            float mu = s1 * (1.f / 256.f);
            float var = fmaxf(s2 * (1.f / 256.f) - mu * mu, 0.f);
            musig[r][0] = mu; musig[r][1] = rsqrtf(var + LN_EPS);
        }
        __syncthreads();

        float mx[4] = {-1e30f, -1e30f, -1e30f, -1e30f};
        #pragma unroll
        for (int mt = 0; mt < 4; ++mt) {
            #pragma unroll
            for (int reg = 0; reg < 4; ++reg) {
                int r = mt * 16 + quad * 4 + reg;
                float mu = musig[r][0], rs = musig[r][1];
                #pragma unroll
                for (int nt = 0; nt < 4; ++nt) {
                    float v = fmaf((acc[mt][nt][reg] - mu) * rs, g2f[nt], be2f[nt]);
                    mx[nt] = fmaxf(mx[nt], v);
                }
            }
        }
        #pragma unroll
        for (int nt = 0; nt < 4; ++nt) {
            mx[nt] = fmaxf(mx[nt], __shfl_xor(mx[nt], 16));
            mx[nt] = fmaxf(mx[nt], __shfl_xor(mx[nt], 32));
        }
        if (quad == 0) {
            #pragma unroll
            for (int nt = 0; nt < 4; ++nt)
                atomicMax(pooled + b * 256 + wv * 64 + nt * 16 + lo16, fenc(mx[nt]));
        }
    }
}

// ---------------- K_final: two tiny MLPs on pooled [4,256] -----------------
__global__ __launch_bounds__(256) void k_final(
    const unsigned int* __restrict__ pooled,
    const float* __restrict__ pw1, const float* __restrict__ pb1,
    const float* __restrict__ pg1, const float* __restrict__ pbe1,
    const float* __restrict__ pw2, const float* __restrict__ pb2,
    const float* __restrict__ pg2, const float* __restrict__ pbe2,
    float* __restrict__ out)
{
    __shared__ float xb[256];
    __shared__ float red2[8];
    int c = threadIdx.x;
    int b = blockIdx.x;
    xb[c] = fdec(pooled[b * 256 + c]);
    __syncthreads();

    float a = pb1[c];
    #pragma unroll 8
    for (int k = 0; k < 256; ++k) a = fmaf(xb[k], pw1[(size_t)k * 256 + c], a);
    float s1 = a, s2 = a * a;
    #pragma unroll
    for (int m_ = 1; m_ <= 32; m_ <<= 1) { s1 += __shfl_xor(s1, m_); s2 += __shfl_xor(s2, m_); }
    if ((c & 63) == 0) { red2[(c >> 6) * 2] = s1; red2[(c >> 6) * 2 + 1] = s2; }
    __syncthreads();
    s1 = red2[0] + red2[2] + red2[4] + red2[6];
    s2 = red2[1] + red2[3] + red2[5] + red2[7];
    float mu = s1 * (1.f / 256.f);
    float rs = rsqrtf(fmaxf(s2 * (1.f / 256.f) - mu * mu, 0.f) + LN_EPS);
    float h = gelu_fast(fmaf((a - mu) * rs, pg1[c], pbe1[c]));
    __syncthreads();
    xb[c] = h;
    __syncthreads();

    float a2 = pb2[c];
    #pragma unroll 8
    for (int k = 0; k < 256; ++k) a2 = fmaf(xb[k], pw2[(size_t)k * 256 + c], a2);
    s1 = a2; s2 = a2 * a2;
    #pragma unroll
    for (int m_ = 1; m_ <= 32; m_ <<= 1) { s1 += __shfl_xor(s1, m_); s2 += __shfl_xor(s2, m_); }
    if ((c & 63) == 0) { red2[(c >> 6) * 2] = s1; red2[(c >> 6) * 2 + 1] = s2; }
    __syncthreads();
    s1 = red2[0] + red2[2] + red2[4] + red2[6];
    s2 = red2[1] + red2[3] + red2[5] + red2[7];
    mu = s1 * (1.f / 256.f);
    rs = rsqrtf(fmaxf(s2 * (1.f / 256.f) - mu * mu, 0.f) + LN_EPS);
    out[b * 256 + c] = fmaf((a2 - mu) * rs, pg2[c], pbe2[c]);
}

// ---------------- launch ---------------------------------------------------
extern "C" void kernel_launch(void* const* d_in, const int* in_sizes, int n_in,
                              void* d_out, int out_size, void* d_ws, size_t ws_size,
                              hipStream_t stream)
{
    char* ws = (char*)d_ws;
    unsigned short* w2T    = (unsigned short*)ws;                      // 128 KB
    unsigned short* w1T    = (unsigned short*)(ws + (128u << 10));     // 96 KB
    unsigned int*   pooled = (unsigned int*)(ws + (224u << 10));       // 4 KB

    k_prep<<<29, 256, 0, stream>>>((const float*)d_in[2], (const float*)d_in[6],
                                   w2T, w1T, pooled);
    k_main<<<8192, 256, 0, stream>>>((const float*)d_in[0], (const float*)d_in[1],
                                     w1T, w2T,
                                     (const float*)d_in[3], (const float*)d_in[4],
                                     (const float*)d_in[5],
                                     (const float*)d_in[7], (const float*)d_in[8],
                                     (const float*)d_in[9], pooled);
    k_final<<<4, 256, 0, stream>>>(pooled,
                                   (const float*)d_in[10], (const float*)d_in[11],
                                   (const float*)d_in[12], (const float*)d_in[13],
                                   (const float*)d_in[14], (const float*)d_in[15],
                                   (const float*)d_in[16], (const float*)d_in[17],
                                   (float*)d_out);
}